// Round 7
// baseline (35.160 us; speedup 1.0000x reference)
//
#include <hip/hip_runtime.h>
#include <hip/hip_bf16.h>

#define N_NODES 100000
#define T_DIM 64
#define D_DIM 128
#define M_MATS 8
#define CROSS_PRUNE 0.1f
#define WPLANE (T_DIM * D_DIM)   // 8192 elems per split plane

typedef __attribute__((ext_vector_type(8))) short bf16x8;    // MFMA A/B fragment
typedef __attribute__((ext_vector_type(4))) float f32x4;     // MFMA accumulator
typedef __attribute__((ext_vector_type(8))) unsigned short ushort8;

// RNE 3-level split via native casts (compiler emits v_cvt_pk_bf16_f32 pairs).
// r1 = v - bf(v), r2 = r1 - bf(r1) are exact in f32.
__device__ __forceinline__ void split3(float v, unsigned short& h,
                                       unsigned short& m, unsigned short& l) {
    __hip_bfloat16 bh = __float2bfloat16(v);
    float fh = __bfloat162float(bh);
    float r1 = v - fh;
    __hip_bfloat16 bm = __float2bfloat16(r1);
    float fm = __bfloat162float(bm);
    float r2 = r1 - fm;
    __hip_bfloat16 bl = __float2bfloat16(r2);
    h = __builtin_bit_cast(unsigned short, bh);
    m = __builtin_bit_cast(unsigned short, bm);
    l = __builtin_bit_cast(unsigned short, bl);
}

// ---- Kernel 1: w[t][d] = sum_m head_w[m]*mats[m][t][d], split 3-level -> wh/wm/wl ----
__global__ __launch_bounds__(256) void wsplit_kernel(const float* __restrict__ mats,
                                                     const float* __restrict__ head_w,
                                                     unsigned short* __restrict__ wh,
                                                     unsigned short* __restrict__ wm,
                                                     unsigned short* __restrict__ wl) {
    int i = blockIdx.x * 256 + threadIdx.x;
    if (i < WPLANE) {
        float acc = 0.f;
#pragma unroll
        for (int m = 0; m < M_MATS; ++m)
            acc += head_w[m] * mats[m * WPLANE + i];
        unsigned short h, mm, l;
        split3(acc, h, mm, l);
        wh[i] = h; wm[i] = mm; wl[i] = l;
    }
}

// ---- Kernel 2: 3-level bf16-split MFMA GEMM + sigmoid + prune, single-pass LDS ----
// Block: 256 thr (4 waves) owns 64 n; wave tg owns t in [tg*16, tg*16+16).
// x split hi/mid/lo into 3 LDS planes [64][128] bf16 (16 KB each, 48 KB total),
// XOR-swizzled byte ^= (row&7)<<4: ushort8 writes and b128 reads both at the
// 8-access/bank floor. One barrier. W fragments preloaded from kernel-1 planes.
__global__ __launch_bounds__(256, 3) void cross_kernel(const float* __restrict__ x,
                                                       const unsigned short* __restrict__ wh,
                                                       const unsigned short* __restrict__ wm,
                                                       const unsigned short* __restrict__ wl,
                                                       const float* __restrict__ head_b_p,
                                                       float* __restrict__ out) {
    __shared__ unsigned short xh[WPLANE];
    __shared__ unsigned short xm[WPLANE];
    __shared__ unsigned short xl[WPLANE];

    const int tid = threadIdx.x;
    const int n0 = blockIdx.x * 64;
    const int lane = tid & 63;
    const int tg = tid >> 6;
    const int r = lane & 15;    // A row / B col within 16
    const int q = lane >> 4;    // k sub-block / C row group

    // ---- x global loads: row = tid>>2, cols (tid&3)*32 .. +32 ----
    const int srow = tid >> 2;
    const int c4 = tid & 3;
    const int gn_s = n0 + srow;
    const float* xrow = x + (size_t)gn_s * D_DIM + c4 * 32;

    float4 p[8];
#pragma unroll
    for (int j = 0; j < 8; ++j) {
        p[j] = make_float4(0.f, 0.f, 0.f, 0.f);
        if (gn_s < N_NODES)
            p[j] = *reinterpret_cast<const float4*>(xrow + j * 4);
    }

    // ---- A fragments: preload (latency hides under split VALU below) ----
    bf16x8 ah[4], am[4], al[4];
#pragma unroll
    for (int k4 = 0; k4 < 4; ++k4) {
        int eo = (tg * 16 + r) * D_DIM + k4 * 32 + q * 8;
        ah[k4] = *reinterpret_cast<const bf16x8*>(wh + eo);
        am[k4] = *reinterpret_cast<const bf16x8*>(wm + eo);
        al[k4] = *reinterpret_cast<const bf16x8*>(wl + eo);
    }

    // ---- split x and store swizzled: 4 ushort8 units per plane per thread ----
    {
        float fv[32];
#pragma unroll
        for (int j = 0; j < 8; ++j) {
            fv[j * 4 + 0] = p[j].x; fv[j * 4 + 1] = p[j].y;
            fv[j * 4 + 2] = p[j].z; fv[j * 4 + 3] = p[j].w;
        }
#pragma unroll
        for (int u = 0; u < 4; ++u) {
            ushort8 H, M, L;
#pragma unroll
            for (int e = 0; e < 8; ++e) {
                unsigned short h_, m_, l_;
                split3(fv[u * 8 + e], h_, m_, l_);
                H[e] = h_; M[e] = m_; L[e] = l_;
            }
            int unit = srow * 16 + c4 * 4 + u;              // 16B units, [64][128] plane
            int byte = (unit << 4) ^ ((srow & 7) << 4);
            *reinterpret_cast<ushort8*>(reinterpret_cast<char*>(xh) + byte) = H;
            *reinterpret_cast<ushort8*>(reinterpret_cast<char*>(xm) + byte) = M;
            *reinterpret_cast<ushort8*>(reinterpret_cast<char*>(xl) + byte) = L;
        }
    }
    __syncthreads();

    // ---- MFMA: 4 k-tiles x (load 12 B-frags, 24 MFMAs nt-inner) ----
    f32x4 acc[4];
#pragma unroll
    for (int nt = 0; nt < 4; ++nt) acc[nt] = (f32x4){0.f, 0.f, 0.f, 0.f};

#pragma unroll
    for (int k4 = 0; k4 < 4; ++k4) {
        bf16x8 bh[4], bm[4], bl[4];
#pragma unroll
        for (int nt = 0; nt < 4; ++nt) {
            int eo = (nt * 16 + r) * D_DIM + k4 * 32 + q * 8;
            int byte = (eo << 1) ^ ((r & 7) << 4);
            bh[nt] = *reinterpret_cast<const bf16x8*>(reinterpret_cast<const char*>(xh) + byte);
            bm[nt] = *reinterpret_cast<const bf16x8*>(reinterpret_cast<const char*>(xm) + byte);
            bl[nt] = *reinterpret_cast<const bf16x8*>(reinterpret_cast<const char*>(xl) + byte);
        }
        // product-outer / nt-inner: acc reuse distance 4 (breaks MFMA dep chain)
#pragma unroll
        for (int nt = 0; nt < 4; ++nt)
            acc[nt] = __builtin_amdgcn_mfma_f32_16x16x32_bf16(ah[k4], bh[nt], acc[nt], 0, 0, 0);
#pragma unroll
        for (int nt = 0; nt < 4; ++nt)
            acc[nt] = __builtin_amdgcn_mfma_f32_16x16x32_bf16(ah[k4], bm[nt], acc[nt], 0, 0, 0);
#pragma unroll
        for (int nt = 0; nt < 4; ++nt)
            acc[nt] = __builtin_amdgcn_mfma_f32_16x16x32_bf16(am[k4], bh[nt], acc[nt], 0, 0, 0);
#pragma unroll
        for (int nt = 0; nt < 4; ++nt)
            acc[nt] = __builtin_amdgcn_mfma_f32_16x16x32_bf16(ah[k4], bl[nt], acc[nt], 0, 0, 0);
#pragma unroll
        for (int nt = 0; nt < 4; ++nt)
            acc[nt] = __builtin_amdgcn_mfma_f32_16x16x32_bf16(al[k4], bh[nt], acc[nt], 0, 0, 0);
#pragma unroll
        for (int nt = 0; nt < 4; ++nt)
            acc[nt] = __builtin_amdgcn_mfma_f32_16x16x32_bf16(am[k4], bm[nt], acc[nt], 0, 0, 0);
    }

    // ---- epilogue: sigmoid + prune + store (C: col=r -> n, row=q*4+i -> t) ----
    const float hb = head_b_p[0];
#pragma unroll
    for (int nt = 0; nt < 4; ++nt) {
        int n = n0 + nt * 16 + r;
        if (n < N_NODES) {
#pragma unroll
            for (int i = 0; i < 4; ++i) {
                int t = tg * 16 + q * 4 + i;
                float v = acc[nt][i] + hb;
                float s = 1.0f / (1.0f + __expf(-v));
                if (s < CROSS_PRUNE) s = 0.0f;
                out[(size_t)t * N_NODES + n] = s;
            }
        }
    }
}

extern "C" void kernel_launch(void* const* d_in, const int* in_sizes, int n_in,
                              void* d_out, int out_size, void* d_ws, size_t ws_size,
                              hipStream_t stream) {
    const float* x      = (const float*)d_in[0];  // [N, D]
    const float* mats   = (const float*)d_in[1];  // [M, T, D]
    const float* head_w = (const float*)d_in[2];  // [M]
    const float* head_b = (const float*)d_in[3];  // [] (1 element)
    float* out = (float*)d_out;                   // [T, N] f32

    unsigned short* wh = (unsigned short*)d_ws;   // 3 bf16 planes, 16 KB each
    unsigned short* wm = wh + WPLANE;
    unsigned short* wl = wm + WPLANE;

    hipLaunchKernelGGL(wsplit_kernel, dim3((WPLANE + 255) / 256), dim3(256), 0, stream,
                       mats, head_w, wh, wm, wl);

    int nblk = (N_NODES + 63) / 64;   // 1563
    hipLaunchKernelGGL(cross_kernel, dim3(nblk), dim3(256), 0, stream,
                       x, wh, wm, wl, head_b, out);
}

// Round 8
// 33.003 us; speedup vs baseline: 1.0654x; 1.0654x over previous
//
#include <hip/hip_runtime.h>
#include <hip/hip_bf16.h>

#define N_NODES 100000
#define T_DIM 64
#define D_DIM 128
#define M_MATS 8
#define CROSS_PRUNE 0.1f
#define WPLANE (T_DIM * D_DIM)   // 8192 elems per W split plane

typedef __attribute__((ext_vector_type(8))) short bf16x8;    // MFMA A/B fragment
typedef __attribute__((ext_vector_type(4))) float f32x4;     // MFMA accumulator
typedef __attribute__((ext_vector_type(8))) unsigned short ushort8;

// RNE 3-level split via native casts (compiler emits v_cvt_pk_bf16_f32 pairs).
// r1 = v - bf(v), r2 = r1 - bf(r1) are exact in f32 (Sterbenz).
__device__ __forceinline__ void split3(float v, unsigned short& h,
                                       unsigned short& m, unsigned short& l) {
    __hip_bfloat16 bh = __float2bfloat16(v);
    float fh = __bfloat162float(bh);
    float r1 = v - fh;
    __hip_bfloat16 bm = __float2bfloat16(r1);
    float fm = __bfloat162float(bm);
    float r2 = r1 - fm;
    __hip_bfloat16 bl = __float2bfloat16(r2);
    h = __builtin_bit_cast(unsigned short, bh);
    m = __builtin_bit_cast(unsigned short, bm);
    l = __builtin_bit_cast(unsigned short, bl);
}

// ---- Kernel 1: w[t][d] = sum_m head_w[m]*mats[m][t][d], 3-level split -> wh/wm/wl ----
__global__ __launch_bounds__(256) void wsplit_kernel(const float* __restrict__ mats,
                                                     const float* __restrict__ head_w,
                                                     unsigned short* __restrict__ wh,
                                                     unsigned short* __restrict__ wm,
                                                     unsigned short* __restrict__ wl) {
    int i = blockIdx.x * 256 + threadIdx.x;
    if (i < WPLANE) {
        float acc = 0.f;
#pragma unroll
        for (int m = 0; m < M_MATS; ++m)
            acc += head_w[m] * mats[m * WPLANE + i];
        unsigned short h, mm, l;
        split3(acc, h, mm, l);
        wh[i] = h; wm[i] = mm; wl[i] = l;
    }
}

// ---- Kernel 2: 3-level bf16-split MFMA GEMM + sigmoid + prune (R6 structure) ----
// Block: 256 thr (4 waves) owns 64 n; wave tg owns t in [tg*16, tg*16+16).
// x split hi/mid/lo into 3 LDS planes [64][64] bf16 per 64-d half (24 KB total),
// XOR-swizzled byte ^= (row&7)<<4: ushort8 writes AND b128 reads at the
// 8-access/bank floor. W fragments preloaded from kernel-1 bf16 planes (no VALU).
__global__ __launch_bounds__(256, 5) void cross_kernel(const float* __restrict__ x,
                                                       const unsigned short* __restrict__ wh,
                                                       const unsigned short* __restrict__ wm,
                                                       const unsigned short* __restrict__ wl,
                                                       const float* __restrict__ head_b_p,
                                                       float* __restrict__ out) {
    __shared__ unsigned short xh[64 * 64];
    __shared__ unsigned short xm[64 * 64];
    __shared__ unsigned short xl[64 * 64];

    const int tid = threadIdx.x;
    const int n0 = blockIdx.x * 64;
    const int lane = tid & 63;
    const int tg = tid >> 6;
    const int r = lane & 15;    // A row / B col within 16
    const int q = lane >> 4;    // k sub-block / C row group

    // ---- x global loads: row = tid>>2, cols (tid&3)*16 .. +16, both halves ----
    const int srow = tid >> 2;
    const int scol = (tid & 3) * 16;
    const int gn_s = n0 + srow;
    const float* xrow = x + (size_t)gn_s * D_DIM + scol;

    float4 p0[4], p1[4];
#pragma unroll
    for (int j = 0; j < 4; ++j) {
        p0[j] = make_float4(0.f, 0.f, 0.f, 0.f);
        p1[j] = p0[j];
        if (gn_s < N_NODES) {
            p0[j] = *reinterpret_cast<const float4*>(xrow + j * 4);        // half 0
            p1[j] = *reinterpret_cast<const float4*>(xrow + 64 + j * 4);   // half 1
        }
    }

    // split 16 elems and store as 2 swizzled ushort8 per plane
#define SPLIT_STORE16(P)                                                        \
    {                                                                           \
        float fv[16];                                                           \
        _Pragma("unroll")                                                       \
        for (int j = 0; j < 4; ++j) {                                           \
            fv[j * 4 + 0] = (P)[j].x; fv[j * 4 + 1] = (P)[j].y;                 \
            fv[j * 4 + 2] = (P)[j].z; fv[j * 4 + 3] = (P)[j].w;                 \
        }                                                                       \
        _Pragma("unroll")                                                       \
        for (int u = 0; u < 2; ++u) {                                           \
            ushort8 H, M, L;                                                    \
            _Pragma("unroll")                                                   \
            for (int e = 0; e < 8; ++e) {                                       \
                unsigned short h_, m_, l_;                                      \
                split3(fv[u * 8 + e], h_, m_, l_);                              \
                H[e] = h_; M[e] = m_; L[e] = l_;                                \
            }                                                                   \
            int unit = srow * 8 + (tid & 3) * 2 + u;                            \
            int byte = (unit << 4) ^ ((srow & 7) << 4);                         \
            *reinterpret_cast<ushort8*>(reinterpret_cast<char*>(xh) + byte) = H;\
            *reinterpret_cast<ushort8*>(reinterpret_cast<char*>(xm) + byte) = M;\
            *reinterpret_cast<ushort8*>(reinterpret_cast<char*>(xl) + byte) = L;\
        }                                                                       \
    }

    SPLIT_STORE16(p0);
    __syncthreads();

    f32x4 acc[4];
#pragma unroll
    for (int nt = 0; nt < 4; ++nt) acc[nt] = (f32x4){0.f, 0.f, 0.f, 0.f};

#pragma unroll
    for (int half = 0; half < 2; ++half) {
        if (half == 1) {
            __syncthreads();   // half-0 readers done
            SPLIT_STORE16(p1);
            __syncthreads();
        }

        // ---- A fragments: 6 b128 loads from pre-split planes (L2-hit, no VALU) ----
        bf16x8 ah[2], am[2], al[2];
#pragma unroll
        for (int k4 = 0; k4 < 2; ++k4) {
            int eo = (tg * 16 + r) * D_DIM + half * 64 + k4 * 32 + q * 8;
            ah[k4] = *reinterpret_cast<const bf16x8*>(wh + eo);
            am[k4] = *reinterpret_cast<const bf16x8*>(wm + eo);
            al[k4] = *reinterpret_cast<const bf16x8*>(wl + eo);
        }

        // ---- MFMA: per k4, nt in pairs (acc reuse distance 2) ----
#pragma unroll
        for (int k4 = 0; k4 < 2; ++k4) {
#pragma unroll
            for (int np = 0; np < 4; np += 2) {
                bf16x8 bh0, bm0, bl0, bh1, bm1, bl1;
                {
                    int e0 = ((np * 16 + r) * 64 + k4 * 32 + q * 8);
                    int b0 = (e0 << 1) ^ ((r & 7) << 4);
                    int e1 = (((np + 1) * 16 + r) * 64 + k4 * 32 + q * 8);
                    int b1 = (e1 << 1) ^ ((r & 7) << 4);
                    bh0 = *reinterpret_cast<const bf16x8*>(reinterpret_cast<const char*>(xh) + b0);
                    bm0 = *reinterpret_cast<const bf16x8*>(reinterpret_cast<const char*>(xm) + b0);
                    bl0 = *reinterpret_cast<const bf16x8*>(reinterpret_cast<const char*>(xl) + b0);
                    bh1 = *reinterpret_cast<const bf16x8*>(reinterpret_cast<const char*>(xh) + b1);
                    bm1 = *reinterpret_cast<const bf16x8*>(reinterpret_cast<const char*>(xm) + b1);
                    bl1 = *reinterpret_cast<const bf16x8*>(reinterpret_cast<const char*>(xl) + b1);
                }
                acc[np]     = __builtin_amdgcn_mfma_f32_16x16x32_bf16(ah[k4], bh0, acc[np], 0, 0, 0);
                acc[np + 1] = __builtin_amdgcn_mfma_f32_16x16x32_bf16(ah[k4], bh1, acc[np + 1], 0, 0, 0);
                acc[np]     = __builtin_amdgcn_mfma_f32_16x16x32_bf16(ah[k4], bm0, acc[np], 0, 0, 0);
                acc[np + 1] = __builtin_amdgcn_mfma_f32_16x16x32_bf16(ah[k4], bm1, acc[np + 1], 0, 0, 0);
                acc[np]     = __builtin_amdgcn_mfma_f32_16x16x32_bf16(am[k4], bh0, acc[np], 0, 0, 0);
                acc[np + 1] = __builtin_amdgcn_mfma_f32_16x16x32_bf16(am[k4], bh1, acc[np + 1], 0, 0, 0);
                acc[np]     = __builtin_amdgcn_mfma_f32_16x16x32_bf16(ah[k4], bl0, acc[np], 0, 0, 0);
                acc[np + 1] = __builtin_amdgcn_mfma_f32_16x16x32_bf16(ah[k4], bl1, acc[np + 1], 0, 0, 0);
                acc[np]     = __builtin_amdgcn_mfma_f32_16x16x32_bf16(al[k4], bh0, acc[np], 0, 0, 0);
                acc[np + 1] = __builtin_amdgcn_mfma_f32_16x16x32_bf16(al[k4], bh1, acc[np + 1], 0, 0, 0);
                acc[np]     = __builtin_amdgcn_mfma_f32_16x16x32_bf16(am[k4], bm0, acc[np], 0, 0, 0);
                acc[np + 1] = __builtin_amdgcn_mfma_f32_16x16x32_bf16(am[k4], bm1, acc[np + 1], 0, 0, 0);
            }
        }
    }

    // ---- epilogue: sigmoid + prune + store (C: col=r -> n, row=q*4+i -> t) ----
    const float hb = head_b_p[0];
#pragma unroll
    for (int nt = 0; nt < 4; ++nt) {
        int n = n0 + nt * 16 + r;
        if (n < N_NODES) {
#pragma unroll
            for (int i = 0; i < 4; ++i) {
                int t = tg * 16 + q * 4 + i;
                float v = acc[nt][i] + hb;
                float s = 1.0f / (1.0f + __expf(-v));
                if (s < CROSS_PRUNE) s = 0.0f;
                out[(size_t)t * N_NODES + n] = s;
            }
        }
    }
#undef SPLIT_STORE16
}

extern "C" void kernel_launch(void* const* d_in, const int* in_sizes, int n_in,
                              void* d_out, int out_size, void* d_ws, size_t ws_size,
                              hipStream_t stream) {
    const float* x      = (const float*)d_in[0];  // [N, D]
    const float* mats   = (const float*)d_in[1];  // [M, T, D]
    const float* head_w = (const float*)d_in[2];  // [M]
    const float* head_b = (const float*)d_in[3];  // [] (1 element)
    float* out = (float*)d_out;                   // [T, N] f32

    unsigned short* wh = (unsigned short*)d_ws;   // 3 bf16 planes, 16 KB each
    unsigned short* wm = wh + WPLANE;
    unsigned short* wl = wm + WPLANE;

    hipLaunchKernelGGL(wsplit_kernel, dim3((WPLANE + 255) / 256), dim3(256), 0, stream,
                       mats, head_w, wh, wm, wl);

    int nblk = (N_NODES + 63) / 64;   // 1563
    hipLaunchKernelGGL(cross_kernel, dim3(nblk), dim3(256), 0, stream,
                       x, wh, wm, wl, head_b, out);
}